// Round 2
// baseline (375.519 us; speedup 1.0000x reference)
//
#include <hip/hip_runtime.h>

#define SEQ_L 1024
#define BATCH_N 512
#define NTAG 48
#define HALF_BLKS 64   // 64 blocks of 8 slots = 512 slots per direction

__device__ inline float wave_sum_f(float v) {
    #pragma unroll
    for (int off = 32; off > 0; off >>= 1) v += __shfl_xor(v, off, 64);
    return v;
}

__device__ inline int wave_sum_i(int v) {
    #pragma unroll
    for (int off = 32; off > 0; off >>= 1) v += __shfl_xor(v, off, 64);
    return v;
}

// broadcast lane t's value of v to all lanes (addr = t*4, uniform)
__device__ inline float bperm_f(int addr, float v) {
    return __int_as_float(__builtin_amdgcn_ds_bpermute(addr, __float_as_int(v)));
}

// Prefetch 8 emissions + masks for slots s = blk*8+k of direction w.
// fwd (w=0): i = 1+s, valid while s < 511  (steps i=1..511)
// bwd (w=1): i = 1023-s, valid s<=511      (steps i=1023..512)
__device__ inline void prefetch8(float (&eb)[8], int (&mb)[8], int blk, int b, int w,
                                 bool act, int lane,
                                 const float* __restrict__ em,
                                 const int* __restrict__ mask) {
    #pragma unroll
    for (int k = 0; k < 8; ++k) {
        int s = blk * 8 + k;
        int i = (w == 0) ? (1 + s) : (1023 - s);
        bool ok = (blk < HALF_BLKS) && ((w == 0) ? (s < 511) : true);
        eb[k] = (act && ok) ? em[((size_t)i * BATCH_N + b) * NTAG + lane] : 0.0f;
        mb[k] = ok ? mask[i * BATCH_N + b] : 0;
    }
}

// 8 forward steps (scaled-prob domain) + renorm.  p' = (p . Ecol) * exp(e)
__device__ inline void step8_fwd(float& p, float& C,
                                 const float (&eb)[8], const int (&mb)[8],
                                 const float (&Ef)[NTAG], const int (&ba)[NTAG]) {
    #pragma unroll
    for (int k = 0; k < 8; ++k) {
        float a0 = 0.f, a1 = 0.f, a2 = 0.f, a3 = 0.f;
        #pragma unroll
        for (int t = 0; t < NTAG; t += 4) {
            a0 = fmaf(bperm_f(ba[t + 0], p), Ef[t + 0], a0);
            a1 = fmaf(bperm_f(ba[t + 1], p), Ef[t + 1], a1);
            a2 = fmaf(bperm_f(ba[t + 2], p), Ef[t + 2], a2);
            a3 = fmaf(bperm_f(ba[t + 3], p), Ef[t + 3], a3);
        }
        float nxt = ((a0 + a1) + (a2 + a3)) * __expf(eb[k]);
        p = mb[k] ? nxt : p;
    }
    float s = wave_sum_f(p);
    C += __logf(s);
    p *= (1.0f / s);
}

// 8 backward steps + renorm.  u' = E . (exp(e) ∘ u)   (Ef here = exp(trans) ROW)
__device__ inline void step8_bwd(float& u, float& C,
                                 const float (&eb)[8], const int (&mb)[8],
                                 const float (&Ef)[NTAG], const int (&ba)[NTAG]) {
    #pragma unroll
    for (int k = 0; k < 8; ++k) {
        float v = u * __expf(eb[k]);
        float a0 = 0.f, a1 = 0.f, a2 = 0.f, a3 = 0.f;
        #pragma unroll
        for (int t = 0; t < NTAG; t += 4) {
            a0 = fmaf(bperm_f(ba[t + 0], v), Ef[t + 0], a0);
            a1 = fmaf(bperm_f(ba[t + 1], v), Ef[t + 1], a1);
            a2 = fmaf(bperm_f(ba[t + 2], v), Ef[t + 2], a2);
            a3 = fmaf(bperm_f(ba[t + 3], v), Ef[t + 3], a3);
        }
        float nxt = (a0 + a1) + (a2 + a3);
        u = mb[k] ? nxt : u;
    }
    float s = wave_sum_f(u);
    C += __logf(s);
    u *= (1.0f / s);
}

__global__ __launch_bounds__(128, 1) void crf_fwd_kernel(
    const float* __restrict__ emissions,
    const float* __restrict__ start_t,
    const float* __restrict__ end_t,
    const float* __restrict__ trans,
    const int*   __restrict__ tags,
    const int*   __restrict__ mask,
    float*       __restrict__ out_per_batch) {
    const int b = blockIdx.x;
    const int tid = threadIdx.x;
    const int w = tid >> 6;          // 0 = forward wave, 1 = backward wave
    const int lane = tid & 63;
    const bool act = lane < NTAG;

    __shared__ float sh_p[2][NTAG];
    __shared__ float sh_C[2];
    __shared__ float sh_num[2];
    __shared__ int   sh_cnt[2];

    // opaque zero so ba[] stays in persistent VGPRs (not rematerialized v_movs)
    const int zero = (b >> 20);      // always 0, unknown to compiler
    int ba[NTAG];
    #pragma unroll
    for (int t = 0; t < NTAG; ++t) ba[t] = t * 4 + zero;

    // E fragment: fwd lane t' holds column exp(trans[t][lane]); bwd lane t holds row exp(trans[lane][t'])
    float Ef[NTAG];
    #pragma unroll
    for (int t = 0; t < NTAG; ++t) {
        int idx = (w == 0) ? (t * NTAG + lane) : (lane * NTAG + t);
        Ef[t] = act ? __expf(trans[idx]) : 0.0f;
    }

    // init
    float p, C = 0.0f;
    if (w == 0) {
        p = act ? __expf(start_t[lane] + emissions[(size_t)b * NTAG + lane]) : 0.0f;
    } else {
        p = act ? __expf(end_t[lane]) : 0.0f;
    }

    // main scan: 64 blocks of 8 slots, double-buffer prefetched
    float eA[8], eB[8];
    int   mA[8], mB[8];
    prefetch8(eA, mA, 0, b, w, act, lane, emissions, mask);
    prefetch8(eB, mB, 1, b, w, act, lane, emissions, mask);
    if (w == 0) {
        for (int blk = 0; blk < HALF_BLKS; blk += 2) {
            step8_fwd(p, C, eA, mA, Ef, ba);
            prefetch8(eA, mA, blk + 2, b, 0, act, lane, emissions, mask);
            step8_fwd(p, C, eB, mB, Ef, ba);
            prefetch8(eB, mB, blk + 3, b, 0, act, lane, emissions, mask);
        }
    } else {
        for (int blk = 0; blk < HALF_BLKS; blk += 2) {
            step8_bwd(p, C, eA, mA, Ef, ba);
            prefetch8(eA, mA, blk + 2, b, 1, act, lane, emissions, mask);
            step8_bwd(p, C, eB, mB, Ef, ba);
            prefetch8(eB, mB, blk + 3, b, 1, act, lane, emissions, mask);
        }
    }

    // numerator: wave w covers i in [w*512, w*512+511], 64 lanes x 8 iters
    float numpart = 0.0f;
    int cnt = 0;
    #pragma unroll
    for (int j = 0; j < 8; ++j) {
        int i = w * 512 + j * 64 + lane;
        int tag_i = tags[(size_t)i * BATCH_N + b];
        int m = mask[i * BATCH_N + b];
        cnt += (m != 0);
        if (i == 0) {
            numpart += start_t[tag_i] + emissions[(size_t)b * NTAG + tag_i];
        } else if (m) {
            int tag_p = tags[(size_t)(i - 1) * BATCH_N + b];
            numpart += trans[tag_p * NTAG + tag_i] +
                       emissions[((size_t)i * BATCH_N + b) * NTAG + tag_i];
        }
    }
    float num = wave_sum_f(numpart);
    int cnth = wave_sum_i(cnt);

    // exchange via LDS
    if (act) sh_p[w][lane] = p;
    if (lane == 0) { sh_C[w] = C; sh_num[w] = num; sh_cnt[w] = cnth; }
    __syncthreads();

    if (w == 0) {
        float dot = act ? p * sh_p[1][lane] : 0.0f;
        float zs = wave_sum_f(dot);
        float log_z = sh_C[0] + sh_C[1] + __logf(zs);
        int seq_len = sh_cnt[0] + sh_cnt[1];
        int last_tag = tags[(size_t)(seq_len - 1) * BATCH_N + b];
        float num_tot = sh_num[0] + sh_num[1] + end_t[last_tag];
        if (lane == 0) out_per_batch[b] = log_z - num_tot;   // = -llh[b]
    }
}

__global__ __launch_bounds__(512) void reduce512_kernel(
    const float* __restrict__ v, float* __restrict__ out) {
    float x = v[threadIdx.x];
    x = wave_sum_f(x);
    __shared__ float ws[8];
    int w = threadIdx.x >> 6;
    if ((threadIdx.x & 63) == 0) ws[w] = x;
    __syncthreads();
    if (threadIdx.x == 0) {
        float t = 0.0f;
        #pragma unroll
        for (int k = 0; k < 8; ++k) t += ws[k];
        *out = t;
    }
}

extern "C" void kernel_launch(void* const* d_in, const int* in_sizes, int n_in,
                              void* d_out, int out_size, void* d_ws, size_t ws_size,
                              hipStream_t stream) {
    const float* emissions = (const float*)d_in[0];
    const float* start_t   = (const float*)d_in[1];
    const float* end_t     = (const float*)d_in[2];
    const float* trans     = (const float*)d_in[3];
    const int*   tags      = (const int*)d_in[4];
    const int*   mask      = (const int*)d_in[5];
    float* per_batch = (float*)d_ws;

    crf_fwd_kernel<<<BATCH_N, 128, 0, stream>>>(emissions, start_t, end_t, trans,
                                                tags, mask, per_batch);
    reduce512_kernel<<<1, 512, 0, stream>>>(per_batch, (float*)d_out);
}

// Round 4
// 243.375 us; speedup vs baseline: 1.5430x; 1.5430x over previous
//
#include <hip/hip_runtime.h>

#define SEQ_L 1024
#define BATCH_N 512
#define NTAG 48
#define HALF_BLKS 64   // 64 blocks of 8 slots = 512 slots per direction

__device__ inline float wave_sum_f(float v) {
    #pragma unroll
    for (int off = 32; off > 0; off >>= 1) v += __shfl_xor(v, off, 64);
    return v;
}

__device__ inline int wave_sum_i(int v) {
    #pragma unroll
    for (int off = 32; off > 0; off >>= 1) v += __shfl_xor(v, off, 64);
    return v;
}

// x += (x shifted right by K lanes within each 16-lane row), via DPP (VALU pipe)
template <int CTRL>
__device__ inline float dpp_add(float x) {
    int m = __builtin_amdgcn_update_dpp(0, __float_as_int(x), CTRL, 0xF, 0xF, true);
    return x + __int_as_float(m);
}

// sum within each 16-lane row; after this, lane 16*r holds sum of lanes [16r,16r+15]
__device__ inline float row16_sum(float x) {
    x = dpp_add<0x111>(x);   // row_shr:1
    x = dpp_add<0x112>(x);   // row_shr:2
    x = dpp_add<0x114>(x);   // row_shr:4
    x = dpp_add<0x118>(x);   // row_shr:8
    return x;
}

// wave-uniform sum of p (p nonzero only in lanes 0..47), cheap VALU-only path
__device__ inline float psum48(float p) {
    float r = row16_sum(p);
    float s0 = __int_as_float(__builtin_amdgcn_readlane(__float_as_int(r), 0));
    float s1 = __int_as_float(__builtin_amdgcn_readlane(__float_as_int(r), 16));
    float s2 = __int_as_float(__builtin_amdgcn_readlane(__float_as_int(r), 32));
    return (s0 + s1) + s2;
}

// 48-way broadcast matvec: out[lane] = sum_t src[t] * Ef[t]
// Grouped 12 readlanes -> 12 fmas so SGPR writes are >=24cyc before reads.
__device__ inline float matvec_bcast(float src, const float (&Ef)[NTAG]) {
    float a0 = 0.f, a1 = 0.f, a2 = 0.f, a3 = 0.f;
    int si = __float_as_int(src);
    #pragma unroll
    for (int g = 0; g < 4; ++g) {
        float s[12];
        #pragma unroll
        for (int j = 0; j < 12; ++j)
            s[j] = __int_as_float(__builtin_amdgcn_readlane(si, g * 12 + j));
        __builtin_amdgcn_sched_barrier(0);
        #pragma unroll
        for (int j = 0; j < 12; j += 4) {
            a0 = fmaf(s[j + 0], Ef[g * 12 + j + 0], a0);
            a1 = fmaf(s[j + 1], Ef[g * 12 + j + 1], a1);
            a2 = fmaf(s[j + 2], Ef[g * 12 + j + 2], a2);
            a3 = fmaf(s[j + 3], Ef[g * 12 + j + 3], a3);
        }
        __builtin_amdgcn_sched_barrier(0);
    }
    return (a0 + a1) + (a2 + a3);
}

// Prefetch 8 emissions + masks for slots s = blk*8+k of direction w.
// fwd (w=0): i = 1+s, valid while s < 511  (steps i=1..511)
// bwd (w=1): i = 1023-s, valid s<=511      (steps i=1023..512)
__device__ inline void prefetch8(float (&eb)[8], int (&mb)[8], int blk, int b, int w,
                                 bool act, int lane,
                                 const float* __restrict__ em,
                                 const int* __restrict__ mask) {
    #pragma unroll
    for (int k = 0; k < 8; ++k) {
        int s = blk * 8 + k;
        int i = (w == 0) ? (1 + s) : (1023 - s);
        bool ok = (blk < HALF_BLKS) && ((w == 0) ? (s < 511) : true);
        eb[k] = (act && ok) ? em[((size_t)i * BATCH_N + b) * NTAG + lane] : 0.0f;
        mb[k] = ok ? mask[i * BATCH_N + b] : 0;
    }
}

// 8 scan steps (scaled-prob domain) + one renorm.  DIR=0 fwd, DIR=1 bwd.
// fwd: p' = (E^T p) * exp(e)      (Ef = column of exp(trans) for this lane)
// bwd: u' = E (exp(e) o u)        (Ef = row of exp(trans) for this lane)
template <int DIR>
__device__ inline void step8(float& p, float& C,
                             const float (&eb)[8], const int (&mb)[8],
                             const float (&Ef)[NTAG]) {
    float fe[8];
    #pragma unroll
    for (int k = 0; k < 8; ++k) fe[k] = __expf(eb[k]);
    #pragma unroll
    for (int k = 0; k < 8; ++k) {
        float src = (DIR == 0) ? p : p * fe[k];
        float r = matvec_bcast(src, Ef);
        float nxt = (DIR == 0) ? r * fe[k] : r;
        p = mb[k] ? nxt : p;
    }
    float s = psum48(p);
    C += __logf(s);
    p *= __builtin_amdgcn_rcpf(s);
}

__global__ __launch_bounds__(128, 1) void crf_fwd_kernel(
    const float* __restrict__ emissions,
    const float* __restrict__ start_t,
    const float* __restrict__ end_t,
    const float* __restrict__ trans,
    const int*   __restrict__ tags,
    const int*   __restrict__ mask,
    float*       __restrict__ out_per_batch) {
    const int b = blockIdx.x;
    const int tid = threadIdx.x;
    const int w = tid >> 6;          // 0 = forward wave, 1 = backward wave
    const int lane = tid & 63;
    const bool act = lane < NTAG;

    __shared__ float sh_p[2][NTAG];
    __shared__ float sh_C[2];
    __shared__ float sh_num[2];
    __shared__ int   sh_cnt[2];

    // E fragment: fwd lane t' holds column exp(trans[t][lane]); bwd lane t holds row exp(trans[lane][t'])
    float Ef[NTAG];
    #pragma unroll
    for (int t = 0; t < NTAG; ++t) {
        int idx = (w == 0) ? (t * NTAG + lane) : (lane * NTAG + t);
        Ef[t] = act ? __expf(trans[idx]) : 0.0f;
    }

    // init
    float p, C = 0.0f;
    if (w == 0) {
        p = act ? __expf(start_t[lane] + emissions[(size_t)b * NTAG + lane]) : 0.0f;
    } else {
        p = act ? __expf(end_t[lane]) : 0.0f;
    }

    // main scan: 64 blocks of 8 slots, double-buffer prefetched
    float eA[8], eB[8];
    int   mA[8], mB[8];
    prefetch8(eA, mA, 0, b, w, act, lane, emissions, mask);
    prefetch8(eB, mB, 1, b, w, act, lane, emissions, mask);
    if (w == 0) {
        for (int blk = 0; blk < HALF_BLKS; blk += 2) {
            step8<0>(p, C, eA, mA, Ef);
            prefetch8(eA, mA, blk + 2, b, 0, act, lane, emissions, mask);
            step8<0>(p, C, eB, mB, Ef);
            prefetch8(eB, mB, blk + 3, b, 0, act, lane, emissions, mask);
        }
    } else {
        for (int blk = 0; blk < HALF_BLKS; blk += 2) {
            step8<1>(p, C, eA, mA, Ef);
            prefetch8(eA, mA, blk + 2, b, 1, act, lane, emissions, mask);
            step8<1>(p, C, eB, mB, Ef);
            prefetch8(eB, mB, blk + 3, b, 1, act, lane, emissions, mask);
        }
    }

    // numerator: wave w covers i in [w*512, w*512+511], 64 lanes x 8 iters
    float numpart = 0.0f;
    int cnt = 0;
    #pragma unroll
    for (int j = 0; j < 8; ++j) {
        int i = w * 512 + j * 64 + lane;
        int tag_i = tags[(size_t)i * BATCH_N + b];
        int m = mask[i * BATCH_N + b];
        cnt += (m != 0);
        if (i == 0) {
            numpart += start_t[tag_i] + emissions[(size_t)b * NTAG + tag_i];
        } else if (m) {
            int tag_p = tags[(size_t)(i - 1) * BATCH_N + b];
            numpart += trans[tag_p * NTAG + tag_i] +
                       emissions[((size_t)i * BATCH_N + b) * NTAG + tag_i];
        }
    }
    float num = wave_sum_f(numpart);
    int cnth = wave_sum_i(cnt);

    // exchange via LDS
    if (act) sh_p[w][lane] = p;
    if (lane == 0) { sh_C[w] = C; sh_num[w] = num; sh_cnt[w] = cnth; }
    __syncthreads();

    if (w == 0) {
        float dot = act ? p * sh_p[1][lane] : 0.0f;
        float zs = wave_sum_f(dot);
        float log_z = sh_C[0] + sh_C[1] + __logf(zs);
        int seq_len = sh_cnt[0] + sh_cnt[1];
        int last_tag = tags[(size_t)(seq_len - 1) * BATCH_N + b];
        float num_tot = sh_num[0] + sh_num[1] + end_t[last_tag];
        if (lane == 0) out_per_batch[b] = log_z - num_tot;   // = -llh[b]
    }
}

__global__ __launch_bounds__(512) void reduce512_kernel(
    const float* __restrict__ v, float* __restrict__ out) {
    float x = v[threadIdx.x];
    x = wave_sum_f(x);
    __shared__ float ws[8];
    int w = threadIdx.x >> 6;
    if ((threadIdx.x & 63) == 0) ws[w] = x;
    __syncthreads();
    if (threadIdx.x == 0) {
        float t = 0.0f;
        #pragma unroll
        for (int k = 0; k < 8; ++k) t += ws[k];
        *out = t;
    }
}

extern "C" void kernel_launch(void* const* d_in, const int* in_sizes, int n_in,
                              void* d_out, int out_size, void* d_ws, size_t ws_size,
                              hipStream_t stream) {
    const float* emissions = (const float*)d_in[0];
    const float* start_t   = (const float*)d_in[1];
    const float* end_t     = (const float*)d_in[2];
    const float* trans     = (const float*)d_in[3];
    const int*   tags      = (const int*)d_in[4];
    const int*   mask      = (const int*)d_in[5];
    float* per_batch = (float*)d_ws;

    crf_fwd_kernel<<<BATCH_N, 128, 0, stream>>>(emissions, start_t, end_t, trans,
                                                tags, mask, per_batch);
    reduce512_kernel<<<1, 512, 0, stream>>>(per_batch, (float*)d_out);
}

// Round 5
// 236.000 us; speedup vs baseline: 1.5912x; 1.0313x over previous
//
#include <hip/hip_runtime.h>

#define SEQ_L 1024
#define BATCH_N 512
#define NTAG 48
#define HALF_BLKS 64   // 64 blocks of 8 slots = 512 slots per direction

__device__ inline float wave_sum_f(float v) {
    #pragma unroll
    for (int off = 32; off > 0; off >>= 1) v += __shfl_xor(v, off, 64);
    return v;
}

__device__ inline int wave_sum_i(int v) {
    #pragma unroll
    for (int off = 32; off > 0; off >>= 1) v += __shfl_xor(v, off, 64);
    return v;
}

// x += (x shifted right by K lanes within each 16-lane row), via DPP (VALU pipe)
template <int CTRL>
__device__ inline float dpp_add(float x) {
    int m = __builtin_amdgcn_update_dpp(0, __float_as_int(x), CTRL, 0xF, 0xF, true);
    return x + __int_as_float(m);
}

// wave-uniform sum of p (nonzero only in lanes 0..47): row sums + 3 readlanes
__device__ inline float psum48(float p) {
    float x = dpp_add<0x111>(p);   // row_shr:1
    x = dpp_add<0x112>(x);         // row_shr:2
    x = dpp_add<0x114>(x);         // row_shr:4
    x = dpp_add<0x118>(x);         // row_shr:8
    float s0 = __int_as_float(__builtin_amdgcn_readlane(__float_as_int(x), 0));
    float s1 = __int_as_float(__builtin_amdgcn_readlane(__float_as_int(x), 16));
    float s2 = __int_as_float(__builtin_amdgcn_readlane(__float_as_int(x), 32));
    return (s0 + s1) + s2;
}

#define RLF(si, L) __int_as_float(__builtin_amdgcn_readlane((si), L))

// one 12-wide group: 12 independent readlanes, then 12 FMAs (SGPRs aged >=24cyc)
#define MVG(si,T0,T1,T2,T3,T4,T5,T6,T7,T8,T9,T10,T11)                          \
    s0=RLF(si,T0); s1=RLF(si,T1); s2=RLF(si,T2); s3=RLF(si,T3);                \
    s4=RLF(si,T4); s5=RLF(si,T5); s6=RLF(si,T6); s7=RLF(si,T7);                \
    s8=RLF(si,T8); s9=RLF(si,T9); s10=RLF(si,T10); s11=RLF(si,T11);            \
    __builtin_amdgcn_sched_barrier(0);                                         \
    a0=fmaf(s0,E##T0,a0); a1=fmaf(s1,E##T1,a1); a2=fmaf(s2,E##T2,a2); a3=fmaf(s3,E##T3,a3); \
    a0=fmaf(s4,E##T4,a0); a1=fmaf(s5,E##T5,a1); a2=fmaf(s6,E##T6,a2); a3=fmaf(s7,E##T7,a3); \
    a0=fmaf(s8,E##T8,a0); a1=fmaf(s9,E##T9,a1); a2=fmaf(s10,E##T10,a2); a3=fmaf(s11,E##T11,a3); \
    __builtin_amdgcn_sched_barrier(0);

// dst[lane] = sum_t src[t] * E_t   (48-way broadcast matvec, all in registers)
#define MATVEC48(dst, si) {                                                    \
    float a0=0.f,a1=0.f,a2=0.f,a3=0.f;                                         \
    float s0,s1,s2,s3,s4,s5,s6,s7,s8,s9,s10,s11;                               \
    MVG(si,0,1,2,3,4,5,6,7,8,9,10,11)                                          \
    MVG(si,12,13,14,15,16,17,18,19,20,21,22,23)                                \
    MVG(si,24,25,26,27,28,29,30,31,32,33,34,35)                                \
    MVG(si,36,37,38,39,40,41,42,43,44,45,46,47)                                \
    dst = (a0+a1)+(a2+a3); }

// prefetch one slot K of block BLK into named scalars e<S><K>/m<S><K>
#define PF1(S,K,BLK,FWD) {                                                     \
    int s_ = (BLK)*8 + (K);                                                    \
    int i_ = (FWD) ? (1+s_) : (1023-s_);                                       \
    bool ok_ = ((BLK) < HALF_BLKS) && ((FWD) ? (s_ < 511) : true);             \
    e##S##K = (act && ok_) ? em[((size_t)i_*BATCH_N + b)*NTAG + lane] : 0.0f;  \
    m##S##K = ok_ ? maskp[i_*BATCH_N + b] : 0; }

#define PF8(S,BLK,FWD)                                                         \
    PF1(S,0,BLK,FWD) PF1(S,1,BLK,FWD) PF1(S,2,BLK,FWD) PF1(S,3,BLK,FWD)        \
    PF1(S,4,BLK,FWD) PF1(S,5,BLK,FWD) PF1(S,6,BLK,FWD) PF1(S,7,BLK,FWD)

// one scan step.  fwd: p' = (E^T p)*fe    bwd: p' = E (fe o p)
#define STEP1(FWD,FE,MK) {                                                     \
    float src_ = (FWD) ? p : p*(FE);                                           \
    int si_ = __float_as_int(src_);                                            \
    float r_; MATVEC48(r_, si_)                                                \
    float nxt_ = (FWD) ? r_*(FE) : r_;                                         \
    p = (MK) ? nxt_ : p; }

// 8 steps + one renormalization (exp's hoisted off the serial chain)
#define STEP8M(FWD,S) {                                                        \
    float f0_=__expf(e##S##0), f1_=__expf(e##S##1);                            \
    float f2_=__expf(e##S##2), f3_=__expf(e##S##3);                            \
    float f4_=__expf(e##S##4), f5_=__expf(e##S##5);                            \
    float f6_=__expf(e##S##6), f7_=__expf(e##S##7);                            \
    STEP1(FWD,f0_,m##S##0) STEP1(FWD,f1_,m##S##1)                              \
    STEP1(FWD,f2_,m##S##2) STEP1(FWD,f3_,m##S##3)                              \
    STEP1(FWD,f4_,m##S##4) STEP1(FWD,f5_,m##S##5)                              \
    STEP1(FWD,f6_,m##S##6) STEP1(FWD,f7_,m##S##7)                              \
    float sum_ = psum48(p);                                                    \
    C += __logf(sum_);                                                         \
    p *= __builtin_amdgcn_rcpf(sum_); }

#define REP48(M) M(0)M(1)M(2)M(3)M(4)M(5)M(6)M(7)M(8)M(9)M(10)M(11)M(12)M(13)M(14)M(15)M(16)M(17)M(18)M(19)M(20)M(21)M(22)M(23)M(24)M(25)M(26)M(27)M(28)M(29)M(30)M(31)M(32)M(33)M(34)M(35)M(36)M(37)M(38)M(39)M(40)M(41)M(42)M(43)M(44)M(45)M(46)M(47)

#define EDECL(t) float E##t;
#define EINIT(t) E##t = act ? __expf(trans[(t)*rs + lane*cs]) : 0.0f;

__global__ __launch_bounds__(128, 1) void crf_fwd_kernel(
    const float* __restrict__ em,
    const float* __restrict__ start_t,
    const float* __restrict__ end_t,
    const float* __restrict__ trans,
    const int*   __restrict__ tags,
    const int*   __restrict__ maskp,
    float*       __restrict__ out_per_batch) {
    const int b = blockIdx.x;
    const int tid = threadIdx.x;
    const int w = tid >> 6;          // 0 = forward wave, 1 = backward wave
    const int lane = tid & 63;
    const bool act = lane < NTAG;

    __shared__ float sh_p[2][NTAG];
    __shared__ float sh_C[2];
    __shared__ float sh_num[2];
    __shared__ int   sh_cnt[2];

    // E fragment in 48 NAMED scalars (SROA-proof -> guaranteed VGPRs).
    // fwd (w=0): E_t = exp(trans[t][lane])  (column);  bwd: exp(trans[lane][t]) (row)
    const int rs = (w == 0) ? NTAG : 1;
    const int cs = (w == 0) ? 1 : NTAG;
    REP48(EDECL)
    REP48(EINIT)

    // init state
    float p, C = 0.0f;
    if (w == 0) {
        p = act ? __expf(start_t[lane] + em[(size_t)b * NTAG + lane]) : 0.0f;
    } else {
        p = act ? __expf(end_t[lane]) : 0.0f;
    }

    // double-buffered named-scalar prefetch buffers
    float eA0,eA1,eA2,eA3,eA4,eA5,eA6,eA7;
    float eB0,eB1,eB2,eB3,eB4,eB5,eB6,eB7;
    int   mA0,mA1,mA2,mA3,mA4,mA5,mA6,mA7;
    int   mB0,mB1,mB2,mB3,mB4,mB5,mB6,mB7;

    if (w == 0) {
        PF8(A,0,1) PF8(B,1,1)
        #pragma unroll 1
        for (int blk = 0; blk < HALF_BLKS; blk += 2) {
            STEP8M(1,A) PF8(A,blk+2,1)
            STEP8M(1,B) PF8(B,blk+3,1)
        }
    } else {
        PF8(A,0,0) PF8(B,1,0)
        #pragma unroll 1
        for (int blk = 0; blk < HALF_BLKS; blk += 2) {
            STEP8M(0,A) PF8(A,blk+2,0)
            STEP8M(0,B) PF8(B,blk+3,0)
        }
    }

    // numerator: wave w covers i in [w*512, w*512+511], 64 lanes x 8 iters
    float numpart = 0.0f;
    int cnt = 0;
    #pragma unroll
    for (int j = 0; j < 8; ++j) {
        int i = w * 512 + j * 64 + lane;
        int tag_i = tags[(size_t)i * BATCH_N + b];
        int m = maskp[i * BATCH_N + b];
        cnt += (m != 0);
        if (i == 0) {
            numpart += start_t[tag_i] + em[(size_t)b * NTAG + tag_i];
        } else if (m) {
            int tag_p = tags[(size_t)(i - 1) * BATCH_N + b];
            numpart += trans[tag_p * NTAG + tag_i] +
                       em[((size_t)i * BATCH_N + b) * NTAG + tag_i];
        }
    }
    float num = wave_sum_f(numpart);
    int cnth = wave_sum_i(cnt);

    // exchange via LDS, combine halves:  Z = sum_t p_fwd[t] * u_bwd[t]
    if (act) sh_p[w][lane] = p;
    if (lane == 0) { sh_C[w] = C; sh_num[w] = num; sh_cnt[w] = cnth; }
    __syncthreads();

    if (w == 0) {
        float dot = act ? p * sh_p[1][lane] : 0.0f;
        float zs = wave_sum_f(dot);
        float log_z = sh_C[0] + sh_C[1] + __logf(zs);
        int seq_len = sh_cnt[0] + sh_cnt[1];
        int last_tag = tags[(size_t)(seq_len - 1) * BATCH_N + b];
        float num_tot = sh_num[0] + sh_num[1] + end_t[last_tag];
        if (lane == 0) out_per_batch[b] = log_z - num_tot;   // = -llh[b]
    }
}

__global__ __launch_bounds__(512) void reduce512_kernel(
    const float* __restrict__ v, float* __restrict__ out) {
    float x = v[threadIdx.x];
    x = wave_sum_f(x);
    __shared__ float ws[8];
    int w = threadIdx.x >> 6;
    if ((threadIdx.x & 63) == 0) ws[w] = x;
    __syncthreads();
    if (threadIdx.x == 0) {
        float t = 0.0f;
        #pragma unroll
        for (int k = 0; k < 8; ++k) t += ws[k];
        *out = t;
    }
}

extern "C" void kernel_launch(void* const* d_in, const int* in_sizes, int n_in,
                              void* d_out, int out_size, void* d_ws, size_t ws_size,
                              hipStream_t stream) {
    const float* emissions = (const float*)d_in[0];
    const float* start_t   = (const float*)d_in[1];
    const float* end_t     = (const float*)d_in[2];
    const float* trans     = (const float*)d_in[3];
    const int*   tags      = (const int*)d_in[4];
    const int*   mask      = (const int*)d_in[5];
    float* per_batch = (float*)d_ws;

    crf_fwd_kernel<<<BATCH_N, 128, 0, stream>>>(emissions, start_t, end_t, trans,
                                                tags, mask, per_batch);
    reduce512_kernel<<<1, 512, 0, stream>>>(per_batch, (float*)d_out);
}